// Round 5
// baseline (166.456 us; speedup 1.0000x reference)
//
#include <hip/hip_runtime.h>

// Replicate XLA:CPU's exact f32 rounding: no mul+add fusion anywhere
// (hipcc default is -ffp-contract=fast; XLA:CPU emits separate fmul/fadd
// with xla_cpu_enable_fast_math=false). Applies to packed ops too (blocks
// v_pk_fma formation).
#pragma clang fp contract(off)

#define TPB 256

typedef float f32x2 __attribute__((ext_vector_type(2)));

// ---------------------------------------------------------------------------
// Threefry-2x32, key = (0, 42). Partitionable counting: element j <- block
// (x0 = hi = 0, x1 = lo = j); 32-bit draw = bits1 ^ bits2. (Verified r2-r4.)
// ---------------------------------------------------------------------------
__device__ __forceinline__ uint32_t rotl32(uint32_t x, uint32_t n) {
  return (x << n) | (x >> (32u - n));
}

__device__ __forceinline__ uint32_t threefry_draw32(uint32_t j) {
  const uint32_t ks1 = 42u;
  const uint32_t ks2 = 0x1BD11BDAu ^ 42u;  // 0x1BD11BF0
  uint32_t x0 = 0u;        // counts_hi = 0 (+ ks0 = 0)
  uint32_t x1 = j + ks1;   // counts_lo + ks1

#define TFR(r) { x0 += x1; x1 = rotl32(x1, r); x1 ^= x0; }
  TFR(13u) TFR(15u) TFR(26u) TFR(6u)   x0 += ks1; x1 += ks2 + 1u;
  TFR(17u) TFR(29u) TFR(16u) TFR(24u)  x0 += ks2; x1 += 0u  + 2u;
  TFR(13u) TFR(15u) TFR(26u) TFR(6u)   x0 += 0u;  x1 += ks1 + 3u;
  TFR(17u) TFR(29u) TFR(16u) TFR(24u)  x0 += ks1; x1 += ks2 + 4u;
  TFR(13u) TFR(15u) TFR(26u) TFR(6u)   x0 += ks2; x1 += 0u  + 5u;
#undef TFR
  return x0 ^ x1;
}

// ---------------------------------------------------------------------------
// Scalar Cephes/Eigen plog + pexp replicas (XLA:CPU GenerateVF32Log/Exp),
// separate mul/add. Used only by the tiny setup kernel. (Verified r2.)
// ---------------------------------------------------------------------------
__device__ __forceinline__ float xla_logf(float xin) {
  uint32_t bits = __float_as_uint(xin);
  int emm0 = (int)(bits >> 23) - 0x7f;
  float m = __uint_as_float((bits & 0x007fffffu) | 0x3f000000u);
  float e = (float)emm0 + 1.0f;
  bool mask = m < 0.707106781186547524f;
  float tmp = mask ? m : 0.0f;
  m = m - 1.0f;
  e = e - (mask ? 1.0f : 0.0f);
  m = m + tmp;
  float x2 = m * m;
  float x3 = x2 * m;
  float y  =  7.0376836292e-2f * m + -1.1514610310e-1f;
  float y1 = -1.2420140846e-1f * m +  1.4249322787e-1f;
  float y2 =  2.0000714765e-1f * m + -2.4999993993e-1f;
  y  = y  * m +  1.1676998740e-1f;
  y1 = y1 * m + -1.6668057665e-1f;
  y2 = y2 * m +  3.3333331174e-1f;
  y  = y * x3 + y1;
  y  = y * x3 + y2;
  y  = y * x3;
  float t1 = -2.12194440e-4f * e;
  float t2 = 0.5f * x2;
  y = y + t1;
  m = m - t2;
  float t3 = 0.693359375f * e;
  m = m + y;
  m = m + t3;
  return m;
}

__device__ __forceinline__ float xla_expf(float xin) {
  float xc = fminf(xin, 88.3762626647950f);
  xc = fmaxf(xc, -88.3762626647949f);
  float fx = floorf(xc * 1.44269504088896341f + 0.5f);
  float tmp = 0.693359375f * fx;
  float z   = -2.12194440e-4f * fx;
  float x = xc - tmp;
  x = x - z;
  z = x * x;
  float y = x * 1.9875691500e-4f + 1.3981999507e-3f;
  y = y * x + 8.3334519073e-3f;
  y = y * x + 4.1665795894e-2f;
  y = y * x + 1.6666665459e-1f;
  y = y * x + 5.0000001201e-1f;
  y = y * z + x;
  y = y + 1.0f;
  int n = (int)fx;
  float p2n = __uint_as_float((uint32_t)(n + 0x7f) << 23);
  return fmaxf(y * p2n, xin);
}

// ---------------------------------------------------------------------------
// Packed (2-wide) Cephes plog core, SIGN-AGNOSTIC: takes the raw bit patterns
// and computes log(|x|). Mantissa field and bfe-extracted exponent are
// identical for x and -x, so callers can pass a negative value's bits to get
// log(-x) with zero extra instructions. Per-component rounding identical to
// xla_logf (v_pk ops are bit-identical IEEE f32; exponent math exact in int
// domain; verified bit-exact r3/r4). Valid for |x| positive normal.
// ---------------------------------------------------------------------------
__device__ __forceinline__ f32x2 xla_logf_pk_core(uint32_t b0, uint32_t b1) {
  f32x2 m;
  m.x = __uint_as_float((b0 & 0x007fffffu) | 0x3f000000u);  // [0.5, 1)
  m.y = __uint_as_float((b1 & 0x007fffffu) | 0x3f000000u);
  bool mk0 = m.x < 0.707106781186547524f;
  bool mk1 = m.y < 0.707106781186547524f;
  int E0 = (int)((b0 >> 23) & 0xffu);   // bfe: sign-agnostic biased exponent
  int E1 = (int)((b1 >> 23) & 0xffu);
  f32x2 e;
  e.x = (float)(E0 - (mk0 ? 127 : 126));  // exact small-int -> float
  e.y = (float)(E1 - (mk1 ? 127 : 126));
  f32x2 tmp;
  tmp.x = mk0 ? m.x : 0.0f;
  tmp.y = mk1 ? m.y : 0.0f;
  m = m - 1.0f;
  m = m + tmp;

  f32x2 x2 = m * m;
  f32x2 x3 = x2 * m;

  f32x2 y  = m * 7.0376836292e-2f  + -1.1514610310e-1f;
  f32x2 y1 = m * -1.2420140846e-1f +  1.4249322787e-1f;
  f32x2 y2 = m * 2.0000714765e-1f  + -2.4999993993e-1f;
  y  = y  * m +  1.1676998740e-1f;
  y1 = y1 * m + -1.6668057665e-1f;
  y2 = y2 * m +  3.3333331174e-1f;
  y  = y * x3 + y1;
  y  = y * x3 + y2;
  y  = y * x3;

  f32x2 t1 = e * -2.12194440e-4f;
  f32x2 t2 = x2 * 0.5f;
  y = y + t1;
  m = m - t2;
  f32x2 t3 = e * 0.693359375f;
  m = m + y;
  m = m + t3;
  return m;
}

// l2 = log(-log(u)) for two raw draws, bit-exact to the reference chain:
//   f = bitcast((bits>>9)|1.0f) - 1;  u = f==0 ? tiny : f  ==  max(f, tiny)
//   (f in {0} U [2^-23, 1), no NaN => IEEE max == the select, exactly)
//   l1 = log(u) < 0 strictly (u < 1)  =>  log(-l1) via sign-agnostic core.
__device__ __forceinline__ f32x2 log_neg_log_u(uint32_t r0, uint32_t r1) {
  f32x2 f;
  f.x = __uint_as_float((r0 >> 9) | 0x3f800000u);
  f.y = __uint_as_float((r1 >> 9) | 0x3f800000u);
  f = f - 1.0f;                                   // [0, 1)
  float ux = fmaxf(f.x, 1.17549435082228750797e-38f);  // tiny
  float uy = fmaxf(f.y, 1.17549435082228750797e-38f);
  f32x2 l1 = xla_logf_pk_core(__float_as_uint(ux), __float_as_uint(uy));
  return xla_logf_pk_core(__float_as_uint(l1.x), __float_as_uint(l1.y));
}

// ---------------------------------------------------------------------------
// Setup: logp = log_softmax(W.T + b), same Cephes rounding as reference.
// ---------------------------------------------------------------------------
__global__ void setup_logp(const float* __restrict__ W,
                           const float* __restrict__ bvec,
                           float* __restrict__ logp) {
  if (threadIdx.x == 0 && blockIdx.x == 0) {
    for (int c = 0; c < 2; ++c) {
      float x0 = W[0 * 2 + c] + bvec[0];
      float x1 = W[1 * 2 + c] + bvec[1];
      float x2 = W[2 * 2 + c] + bvec[2];
      float mx = fmaxf(fmaxf(fmaxf(-__builtin_inff(), x0), x1), x2);
      float s0 = x0 - mx, s1 = x1 - mx, s2 = x2 - mx;
      float e0 = xla_expf(s0);
      float e1 = xla_expf(s1);
      float e2 = xla_expf(s2);
      float se = (e0 + e1) + e2;
      float lse = xla_logf(se);
      logp[c * 3 + 0] = s0 - lse;
      logp[c * 3 + 1] = s1 - lse;
      logp[c * 3 + 2] = s2 - lse;
    }
  }
}

// Per-element result bundle.
struct ElemOut {
  float u0, w0, w1, l0, l1;
};

// Full pipeline for batch element b: 6 draws at base=6b -> 3 packed gumbel
// pairs -> per-card argmax (strict >, first max wins) -> outputs.
__device__ __forceinline__ ElemOut process_element(uint32_t b, int card,
                                                   const float lp[6]) {
  uint32_t base = b * 6u;
  uint32_t r[6];
#pragma unroll
  for (int k = 0; k < 6; ++k) r[k] = threefry_draw32(base + (uint32_t)k);

  f32x2 s[3];
#pragma unroll
  for (int k = 0; k < 3; ++k) {
    f32x2 l2 = log_neg_log_u(r[k], r[k + 3]);
    f32x2 lpk;
    lpk.x = lp[k];
    lpk.y = lp[3 + k];
    s[k] = lpk - l2;   // == gumbel + logits (add commutative, negation exact)
  }

  // argmax per card, strict > keeps first occurrence (XLA tie rule)
  int a0 = 0; float best0 = s[0].x;
  if (s[1].x > best0) { best0 = s[1].x; a0 = 1; }
  if (s[2].x > best0) { best0 = s[2].x; a0 = 2; }
  int a1 = 0; float best1 = s[0].y;
  if (s[1].y > best1) { best1 = s[1].y; a1 = 1; }
  if (s[2].y > best1) { best1 = s[2].y; a1 = 2; }

  ElemOut o;
  o.l0 = lp[a0];
  o.l1 = lp[3 + a1];
  // u0 = action of the dealt card; beliefs:
  //   a0==a1         -> (0.5, 0.5)
  //   else card==0   -> (1, 0)
  //   else           -> (0, 1)
  bool eq = (a0 == a1);
  bool c0 = (card == 0);
  int u0 = c0 ? a0 : a1;
  o.u0 = (float)u0;
  o.w0 = eq ? 0.5f : (c0 ? 1.0f : 0.0f);
  o.w1 = eq ? 0.5f : (c0 ? 0.0f : 1.0f);
  return o;
}

// ---------------------------------------------------------------------------
// Main: FOUR batch elements per thread (b = 4t .. 4t+3). int4 cards load,
// float4 stores throughout, one bounds check per quad. Requires B % 4 == 0
// (BATCH = 4194304). Output (f32, concat): u0[B] | beliefs[B][2] | log_cf[B][2].
// ---------------------------------------------------------------------------
__global__ void __launch_bounds__(TPB) sample_kernel4(
    const int* __restrict__ cards, const float* __restrict__ lp_g,
    float* __restrict__ out_u0, float* __restrict__ out_beliefs,
    float* __restrict__ out_logcf, int nquads) {
  int t = blockIdx.x * TPB + threadIdx.x;
  if (t >= nquads) return;

  float lp[6];
#pragma unroll
  for (int i = 0; i < 6; ++i) lp[i] = lp_g[i];

  int4 c4 = reinterpret_cast<const int4*>(cards)[t];
  uint32_t b0 = (uint32_t)t * 4u;

  ElemOut e0 = process_element(b0 + 0u, c4.x, lp);
  ElemOut e1 = process_element(b0 + 1u, c4.y, lp);
  ElemOut e2 = process_element(b0 + 2u, c4.z, lp);
  ElemOut e3 = process_element(b0 + 3u, c4.w, lp);

  reinterpret_cast<float4*>(out_u0)[t] = make_float4(e0.u0, e1.u0, e2.u0, e3.u0);
  float4* bel = reinterpret_cast<float4*>(out_beliefs);
  bel[2 * t + 0] = make_float4(e0.w0, e0.w1, e1.w0, e1.w1);
  bel[2 * t + 1] = make_float4(e2.w0, e2.w1, e3.w0, e3.w1);
  float4* lcf = reinterpret_cast<float4*>(out_logcf);
  lcf[2 * t + 0] = make_float4(e0.l0, e0.l1, e1.l0, e1.l1);
  lcf[2 * t + 1] = make_float4(e2.l0, e2.l1, e3.l0, e3.l1);
}

extern "C" void kernel_launch(void* const* d_in, const int* in_sizes, int n_in,
                              void* d_out, int out_size, void* d_ws, size_t ws_size,
                              hipStream_t stream) {
  (void)n_in; (void)out_size; (void)ws_size;
  const int* cards = (const int*)d_in[0];   // (B,) int32
  const float* W   = (const float*)d_in[1]; // (3,2) f32 row-major
  const float* bv  = (const float*)d_in[2]; // (3,)  f32
  float* out = (float*)d_out;               // u0[B] | beliefs[B*2] | log_cf[B*2]
  float* lp  = (float*)d_ws;                // 6 floats scratch

  int B = in_sizes[0];
  int nquads = B >> 2;  // BATCH = 4194304 (divisible by 4)
  setup_logp<<<1, 64, 0, stream>>>(W, bv, lp);
  sample_kernel4<<<(nquads + TPB - 1) / TPB, TPB, 0, stream>>>(
      cards, lp, out, out + (size_t)B, out + (size_t)3 * B, nquads);
}